// Round 10
// baseline (1944.902 us; speedup 1.0000x reference)
//
#include <hip/hip_runtime.h>
#include <hip/hip_bf16.h>
#include <math.h>

#define COUT 64
#define EPS  1e-5f

typedef __hip_bfloat16 bf16;
typedef short  short8  __attribute__((ext_vector_type(8)));
typedef short  short4v __attribute__((ext_vector_type(4)));
typedef float  floatx4 __attribute__((ext_vector_type(4)));

__device__ __forceinline__ short bf16_bits(float f) {
    union { __hip_bfloat16 h; short s; } u;
    u.h = __float2bfloat16(f);
    return u.s;
}
__device__ __forceinline__ float bits_to_f32(short s) {
    union { __hip_bfloat16 h; short s; } u;
    u.s = s;
    return __bfloat162float(u.h);
}

// ---------------- geometry ----------------
// conv1: xpad bf16 NHWC [16][132][260][32]; virtual out 130x260 (valid ow<258)
//        -> h1pad [16][134][262][64] interior at pad 2
// conv2: h1pad -> virtual out 132x262 (valid ow<260) -> h2 [16][132][260][64]
#define NV1   33800                /* 130*260 */
#define NV2   34584                /* 132*262 */
#define XPAD_PLANE  (132*260)
#define H1_PLANE    (134*262)
#define H2_PLANE    (132*260)
#define NPOS1 (16*130*258)
#define NPOS2 (16*132*260)
#define CW1_N (130*258)
#define CW2_N (132*260)

#define CW1_BLK ((CW1_N + 255)/256)   /* 132 */
#define CW2_BLK ((CW2_N + 255)/256)   /* 135 */
#define PK1_BLK (9*1024/256)          /* 36 */
#define PK2_BLK (18*1024/256)         /* 72 */

// ---------------- fused prep: zero stats + cwv1 + cwv2 + pack1 + pack2 ------
// cwv on the VIRTUAL plane [r][Nv] (garbage cols clamped; masked at store)
__device__ __forceinline__ void cwv_body(const float* __restrict__ ah, const float* __restrict__ aw,
                                         float* __restrict__ cwv, int Nv, int Wv,
                                         int Lh, int Lw, int idx) {
    if (idx >= Nv) return;
    int oh = idx / Wv, ow = idx - oh*Wv;
    if (ow > Lw-1) ow = Lw-1;
    if (oh > Lh-1) oh = Lh-1;
    float v0 = ah[0*Lh+oh] + aw[0*Lw+ow];
    float v1 = ah[1*Lh+oh] + aw[1*Lw+ow];
    float v2 = ah[2*Lh+oh] + aw[2*Lw+ow];
    float v3 = ah[3*Lh+oh] + aw[3*Lw+ow];
    float m = fmaxf(fmaxf(v0,v1), fmaxf(v2,v3));
    v0 = __expf(v0-m); v1 = __expf(v1-m); v2 = __expf(v2-m); v3 = __expf(v3-m);
    float inv = 1.f/(v0+v1+v2+v3);
    cwv[0*(size_t)Nv+idx] = v0*inv; cwv[1*(size_t)Nv+idx] = v1*inv;
    cwv[2*(size_t)Nv+idx] = v2*inv; cwv[3*(size_t)Nv+idx] = v3*inv;
}
#define CWV1_BLK ((NV1 + 255)/256)   /* 133 */
#define CWV2_BLK ((NV2 + 255)/256)   /* 136 */

// Apk[((s*16+t)*64+l)*8+j] = A[m=t*16+(l&15)][k=s*32+(l>>4)*8+j], k=tap*CIN+ci
template<int CIN_, int NSLICES>
__device__ __forceinline__ void pack_body(const float* __restrict__ w, short* __restrict__ Apk, int gid) {
    if (gid >= NSLICES*1024) return;
    int l = gid & 63, t = (gid >> 6) & 15, s = gid >> 10;
    int m = t*16 + (l & 15);
    int r = m >> 6, co = m & 63;
    int kbase = s*32 + ((l >> 4) << 3);
    short8 v;
    #pragma unroll
    for (int j = 0; j < 8; ++j) {
        int k = kbase + j;
        int tap = k / CIN_, ci = k % CIN_;
        v[j] = bf16_bits(w[(((size_t)(r*COUT + co))*CIN_ + ci)*9 + tap]);
    }
    *reinterpret_cast<short8*>(Apk + (size_t)gid*8) = v;
}

__global__ void prep_kernel(const float* __restrict__ a1h, const float* __restrict__ a1w,
                            const float* __restrict__ a2h, const float* __restrict__ a2w,
                            const float* __restrict__ w1, const float* __restrict__ w2,
                            float* __restrict__ stats, float* __restrict__ cwv1,
                            float* __restrict__ cwv2, short* __restrict__ Apk1,
                            short* __restrict__ Apk2) {
    int bx = blockIdx.x;
    if (bx == 0) {
        stats[threadIdx.x] = 0.f; stats[threadIdx.x + 256] = 0.f;
    } else if (bx < 1 + CWV1_BLK) {
        cwv_body(a1h, a1w, cwv1, NV1, 260, 130, 258, (bx-1)*256 + threadIdx.x);
    } else if (bx < 1 + CWV1_BLK + CWV2_BLK) {
        cwv_body(a2h, a2w, cwv2, NV2, 262, 132, 260, (bx-(1+CWV1_BLK))*256 + threadIdx.x);
    } else if (bx < 1 + CWV1_BLK + CWV2_BLK + PK1_BLK) {
        pack_body<32, 9>(w1, Apk1, (bx-(1+CWV1_BLK+CWV2_BLK))*256 + threadIdx.x);
    } else {
        pack_body<64,18>(w2, Apk2, (bx-(1+CWV1_BLK+CWV2_BLK+PK1_BLK))*256 + threadIdx.x);
    }
}
#define PREP_BLOCKS (1 + CWV1_BLK + CWV2_BLK + PK1_BLK + PK2_BLK)  /* 378 */

// ---------------- fused: zero h1pad BORDER only + build xpad -----------------
// Interior of h1pad (rows 2..131, cols 2..259) is fully written by conv1, so
// only the 2-wide border needs zeroing (3.2 MB instead of 72 MB).
__global__ void border_xpad_kernel(short* __restrict__ h1p,
                                   const float* __restrict__ x, short* __restrict__ xp) {
    if (blockIdx.x < 16) {
        int b = blockIdx.x;
        short* base = h1p + (size_t)b*H1_PLANE*64;
        short8 z = (short8){0,0,0,0,0,0,0,0};
        // rows 0,1,132,133 full width
        for (int it = threadIdx.x; it < 4*262*8; it += 256) {
            int pos = it >> 3, g = it & 7;
            int rr = pos / 262, cc = pos - rr*262;
            int row = (rr < 2) ? rr : 130 + rr;
            *reinterpret_cast<short8*>(base + ((size_t)row*262 + cc)*64 + g*8) = z;
        }
        // rows 2..131, cols 0,1,260,261
        for (int it = threadIdx.x; it < 130*4*8; it += 256) {
            int pos = it >> 3, g = it & 7;
            int rr = pos >> 2, k = pos & 3;
            int col = (k < 2) ? k : 258 + k;
            *reinterpret_cast<short8*>(base + ((size_t)(rr+2)*262 + col)*64 + g*8) = z;
        }
    } else {
        int row = blockIdx.x - 16;            // b*132 + ih
        int b = row / 132, ih = row - b*132;
        int ci = threadIdx.x & 31, iw0 = threadIdx.x >> 5;
        for (int iw = iw0; iw < 260; iw += 8) {
            float v = 0.f;
            if (ih >= 2 && ih < 130 && iw >= 2 && iw < 258)
                v = x[(((size_t)b*32 + ci)*128 + (ih-2))*256 + (iw-2)];
            xp[((size_t)row*260 + iw)*32 + ci] = bf16_bits(v);
        }
    }
}

// ---------------- direct-global MFMA implicit-GEMM LRLC conv -----------------
// N=64 per block (high-occupancy shape, R3 lineage): block = 4 waves, M=256
// (4 ranks x 64 co), N=64 virtual positions. acc[4][4]=64 AGPR; B loaded
// directly from global NHWC (contiguous 16B per lane, L1 serves the 4-wave
// redundancy); A ping-ponged one slice ahead (issued after B(s) so the MFMAs
// wait vmcnt(4), keeping the prefetch in flight). ~150 regs -> 3 blocks/CU.
template<int CIN_, int NSLICES>
__launch_bounds__(256, 2)
__global__ void lrlc_conv(const short* __restrict__ Bpl, const short* __restrict__ Apk,
                          const float* __restrict__ cwv, const float* __restrict__ bias,
                          short* __restrict__ Out, float* __restrict__ sum, float* __restrict__ sq,
                          int Wv, int Hout, int Wreal, int Nv, int inPlanePos,
                          int outW, int outPlanePos, int outPad) {
    const int tid  = threadIdx.x;
    const int w    = tid >> 6, l = tid & 63;
    const int quad = l >> 4, l15 = l & 15;
    const int b    = blockIdx.y;
    const int n0   = blockIdx.x * 64;

    __shared__ float cwS[256];
    {
        int r = tid >> 6, nn = tid & 63;
        int n = n0 + nn; if (n > Nv-1) n = Nv-1;
        cwS[r*64 + nn] = cwv[(size_t)r*Nv + n];
    }
    __syncthreads();

    const short* Bb = Bpl + (size_t)b*inPlanePos*CIN_;
    int bOff[4];
    #pragma unroll
    for (int j = 0; j < 4; ++j) bOff[j] = (n0 + j*16 + l15)*CIN_ + quad*8;
    const short* Aw = Apk + (size_t)(w*64 + l)*8;

    floatx4 acc[4][4];
    #pragma unroll
    for (int i = 0; i < 4; ++i)
        #pragma unroll
        for (int j = 0; j < 4; ++j)
            acc[i][j] = (floatx4){0.f,0.f,0.f,0.f};

    auto loadA = [&](int s, short8* afr) {
        #pragma unroll
        for (int i = 0; i < 4; ++i)
            afr[i] = *reinterpret_cast<const short8*>(Aw + (size_t)(s*16 + i*4)*512);
    };
    short8 afr[2][4];
    loadA(0, afr[0]);

    #pragma unroll
    for (int s = 0; s < NSLICES; ++s) {
        const int cur = s & 1;
        const int tap = (CIN_ == 32) ? s : (s >> 1);
        const int cb  = (CIN_ == 32) ? 0 : ((s & 1) << 5);
        const int koff = ((tap/3)*Wv + (tap%3))*CIN_ + cb;
        short8 bfr[4];
        #pragma unroll
        for (int j = 0; j < 4; ++j)
            bfr[j] = *reinterpret_cast<const short8*>(Bb + bOff[j] + koff);
        if (s + 1 < NSLICES) loadA(s+1, afr[cur ^ 1]);   // in flight across MFMAs
        #pragma unroll
        for (int i = 0; i < 4; ++i)
            #pragma unroll
            for (int j = 0; j < 4; ++j)
                acc[i][j] = __builtin_amdgcn_mfma_f32_16x16x32_bf16(afr[cur][i], bfr[j], acc[i][j], 0, 0, 0);
    }

    // epilogue: rank-combine, +bias, store bf16x4, fused BN stats (fp32)
    const int co_base = w*16 + quad*4;
    float bs[4];
    #pragma unroll
    for (int rg = 0; rg < 4; ++rg) bs[rg] = bias[co_base + rg];
    float st[4] = {0.f,0.f,0.f,0.f}, st2[4] = {0.f,0.f,0.f,0.f};
    #pragma unroll
    for (int j = 0; j < 4; ++j) {
        int nl = j*16 + l15;
        int n  = n0 + nl;
        int oh = n / Wv, ow = n - oh*Wv;
        bool valid = (ow < Wreal) && (oh < Hout);
        float c0 = cwS[nl], c1 = cwS[64+nl], c2 = cwS[128+nl], c3 = cwS[192+nl];
        short4v pk;
        #pragma unroll
        for (int rg = 0; rg < 4; ++rg) {
            float v = acc[0][j][rg]*c0 + acc[1][j][rg]*c1
                    + acc[2][j][rg]*c2 + acc[3][j][rg]*c3 + bs[rg];
            if (valid) { st[rg] += v; st2[rg] = fmaf(v, v, st2[rg]); }
            pk[rg] = bf16_bits(v);
        }
        if (valid) {
            size_t op = ((size_t)b*outPlanePos + (size_t)(oh + outPad)*outW + (ow + outPad))*(size_t)COUT + co_base;
            *reinterpret_cast<short4v*>(Out + op) = pk;
        }
    }
    #pragma unroll
    for (int m = 1; m < 16; m <<= 1) {
        #pragma unroll
        for (int rg = 0; rg < 4; ++rg) {
            st[rg]  += __shfl_xor(st[rg],  m, 16);
            st2[rg] += __shfl_xor(st2[rg], m, 16);
        }
    }
    if (l15 == 0) {
        #pragma unroll
        for (int rg = 0; rg < 4; ++rg) {
            atomicAdd(&sum[co_base+rg], st[rg]);
            atomicAdd(&sq[co_base+rg],  st2[rg]);
        }
    }
}

__global__ void finalize_kernel(const float* __restrict__ sum, const float* __restrict__ sumsq,
                                const float* __restrict__ g, const float* __restrict__ be,
                                float* __restrict__ A, float* __restrict__ Bc, float cnt) {
    int c = threadIdx.x;
    if (c >= COUT) return;
    float mean = sum[c]/cnt;
    float var  = sumsq[c]/cnt - mean*mean;
    float inv  = rsqrtf(var + EPS);
    float a = g[c]*inv;
    A[c]  = a;
    Bc[c] = fmaf(-mean, a, be[c]);
}

// row-based in-place BN+ReLU on h1pad interior; grid 16*130, block 256
__global__ void bnrelu_rows(short* __restrict__ h, const float* __restrict__ A,
                            const float* __restrict__ Bc) {
    __shared__ float sA[64], sB[64];
    if (threadIdx.x < 64) { sA[threadIdx.x] = A[threadIdx.x]; sB[threadIdx.x] = Bc[threadIdx.x]; }
    __syncthreads();
    int row = blockIdx.x;                 // b*130 + oh
    int b = row / 130, oh = row - b*130;
    short* base = h + ((size_t)(b*134 + oh + 2)*262 + 2)*64;
    const int nvec = 258*64/8;            // 2064
    for (int it = threadIdx.x; it < nvec; it += 256) {
        short8 d = *reinterpret_cast<short8*>(base + it*8);
        int c0 = (it*8) & 63;
        #pragma unroll
        for (int q = 0; q < 8; ++q) {
            float v = bits_to_f32(d[q]);
            int c = c0 + q;
            v = fmaxf(fmaf(v, sA[c], sB[c]), 0.f);
            d[q] = bf16_bits(v);
        }
        *reinterpret_cast<short8*>(base + it*8) = d;
    }
}

// fused BN2+ReLU+3x3/3 maxpool: h2 NHWC -> out fp32 NCHW [16,64,44,86]
__global__ void maxpool_rows(const short* __restrict__ h2, const float* __restrict__ A,
                             const float* __restrict__ Bc, float* __restrict__ out) {
    __shared__ float sA[64], sB[64];
    if (threadIdx.x < 64) { sA[threadIdx.x] = A[threadIdx.x]; sB[threadIdx.x] = Bc[threadIdx.x]; }
    __syncthreads();
    int row = blockIdx.x;                 // b*44 + ph
    int b = row / 44, ph = row - b*44;
    for (int item = threadIdx.x; item < 86*16; item += 256) {
        int cg = item & 15, pw = item >> 4;
        float m[4] = {0.f,0.f,0.f,0.f};
        #pragma unroll
        for (int i = 0; i < 3; ++i) {
            const short* rp = h2 + ((size_t)(b*132 + ph*3 + i)*260 + pw*3)*64 + cg*4;
            #pragma unroll
            for (int j = 0; j < 3; ++j) {
                short4v d = *reinterpret_cast<const short4v*>(rp + j*64);
                #pragma unroll
                for (int q = 0; q < 4; ++q) {
                    int c = cg*4 + q;
                    float v = fmaf(bits_to_f32(d[q]), sA[c], sB[c]);
                    m[q] = fmaxf(m[q], v);
                }
            }
        }
        #pragma unroll
        for (int q = 0; q < 4; ++q)
            out[((size_t)(b*64 + cg*4 + q)*44 + ph)*86 + pw] = m[q];
    }
}

extern "C" void kernel_launch(void* const* d_in, const int* in_sizes, int n_in,
                              void* d_out, int out_size, void* d_ws, size_t ws_size,
                              hipStream_t stream) {
    const float* x   = (const float*)d_in[0];
    const float* w1  = (const float*)d_in[1];
    const float* b1  = (const float*)d_in[2];
    const float* a1h = (const float*)d_in[3];
    const float* a1w = (const float*)d_in[4];
    const float* g1  = (const float*)d_in[5];
    const float* be1 = (const float*)d_in[6];
    const float* w2  = (const float*)d_in[7];
    const float* b2  = (const float*)d_in[8];
    const float* a2h = (const float*)d_in[9];
    const float* a2w = (const float*)d_in[10];
    const float* g2  = (const float*)d_in[11];
    const float* be2 = (const float*)d_in[12];
    float* out = (float*)d_out;

    char* ws = (char*)d_ws;
    float* stats = (float*)ws;                    // 512 floats
    float* sum1 = stats;       float* sq1 = stats + 64;
    float* A1   = stats + 128; float* Bc1 = stats + 192;
    float* sum2 = stats + 256; float* sq2 = stats + 320;
    float* A2   = stats + 384; float* Bc2 = stats + 448;
    float* cwv1 = (float*)(ws + 2048);            // 4*NV1 floats
    float* cwv2 = cwv1 + 4*NV1;                   // 4*NV2 floats
    short* Apk1 = (short*)(cwv2 + 4*NV2);         // 73728 shorts
    short* Apk2 = Apk1 + 73728;                   // 147456 shorts
    short* h1pad = Apk2 + 147456;                 // 16*134*262*64 shorts
    short* xpad  = h1pad + (size_t)16*H1_PLANE*64 + 4096;
    short* h2    = xpad;                          // xpad dead before conv2 writes h2

    prep_kernel<<<PREP_BLOCKS, 256, 0, stream>>>(a1h, a1w, a2h, a2w, w1, w2,
                                                 stats, cwv1, cwv2, Apk1, Apk2);
    border_xpad_kernel<<<16 + 16*132, 256, 0, stream>>>(h1pad, x, xpad);

    // layer 1: xpad [16][132][260][32] -> h1pad [16][134][262][64] (pad 2)
    lrlc_conv<32, 9><<<dim3((NV1+63)/64, 16), 256, 0, stream>>>(
        xpad, Apk1, cwv1, b1, h1pad, sum1, sq1,
        /*Wv*/260, /*Hout*/130, /*Wreal*/258, /*Nv*/NV1, /*inPlanePos*/XPAD_PLANE,
        /*outW*/262, /*outPlanePos*/H1_PLANE, /*outPad*/2);
    finalize_kernel<<<1, 64, 0, stream>>>(sum1, sq1, g1, be1, A1, Bc1, (float)NPOS1);
    bnrelu_rows<<<16*130, 256, 0, stream>>>(h1pad, A1, Bc1);

    // layer 2: h1pad -> h2 [16][132][260][64]
    lrlc_conv<64,18><<<dim3((NV2+63)/64, 16), 256, 0, stream>>>(
        h1pad, Apk2, cwv2, b2, h2, sum2, sq2,
        /*Wv*/262, /*Hout*/132, /*Wreal*/260, /*Nv*/NV2, /*inPlanePos*/H1_PLANE,
        /*outW*/260, /*outPlanePos*/H2_PLANE, /*outPad*/0);
    finalize_kernel<<<1, 64, 0, stream>>>(sum2, sq2, g2, be2, A2, Bc2, (float)NPOS2);

    maxpool_rows<<<16*44, 256, 0, stream>>>(h2, A2, Bc2, out);
}